// Round 13
// baseline (1194.086 us; speedup 1.0000x reference)
//
#include <hip/hip_runtime.h>

#define NN 50000
#define NE 400000
#define DIM 128

typedef __bf16 bf16x8 __attribute__((ext_vector_type(8)));
typedef float f32x4 __attribute__((ext_vector_type(4)));
typedef unsigned short u16;

#define MFMA16 __builtin_amdgcn_mfma_f32_16x16x32_bf16

__device__ __forceinline__ u16 f2b(float f){ __bf16 b=(__bf16)f; return __builtin_bit_cast(u16,b); }
__device__ __forceinline__ float b2f(u16 h){ unsigned u = ((unsigned)h)<<16; return __builtin_bit_cast(float,u); }
__device__ __forceinline__ float sigm(float x){ return 1.0f/(1.0f+__expf(-x)); }
__device__ __forceinline__ float tanh_(float x){ float e=__expf(2.0f*x); return 1.0f-2.0f/(e+1.0f); }
__device__ __forceinline__ bf16x8 ldb8(const u16* p){ return *reinterpret_cast<const bf16x8*>(p); }

#define GLOAD_LDS(gp, lp) __builtin_amdgcn_global_load_lds( \
    (const __attribute__((address_space(1))) void*)(gp),    \
    (__attribute__((address_space(3))) void*)(lp), 16, 0, 0)

// ---------- utility kernels ----------
__global__ void f2b_kernel(const float* __restrict__ in, u16* __restrict__ out, int n4){
  int i = blockIdx.x*blockDim.x + threadIdx.x;
  int st = gridDim.x*blockDim.x;
  for (; i<n4; i+=st){
    float4 v = reinterpret_cast<const float4*>(in)[i];
    ushort4 o = { f2b(v.x), f2b(v.y), f2b(v.z), f2b(v.w) };
    reinterpret_cast<ushort4*>(out)[i] = o;
  }
}

// fused weight prep: all 4 GRU weight converts + aW1 transpose in one launch
__global__ void wprep_kernel(const float* __restrict__ eWih, const float* __restrict__ eWhh,
                             const float* __restrict__ nWih, const float* __restrict__ nWhh,
                             const float* __restrict__ aW1,
                             u16* __restrict__ bWih, u16* __restrict__ bWhh,
                             u16* __restrict__ bnWih, u16* __restrict__ bnWhh,
                             u16* __restrict__ baW1T){
  int i = blockIdx.x*256 + threadIdx.x;        // 1024 blocks x 256 = 262144
  if (i < 98304){ bWih[i] = f2b(eWih[i]); return; }
  i -= 98304;
  if (i < 49152){ bWhh[i] = f2b(eWhh[i]); return; }
  i -= 49152;
  if (i < 49152){ bnWih[i] = f2b(nWih[i]); return; }
  i -= 49152;
  if (i < 49152){ bnWhh[i] = f2b(nWhh[i]); return; }
  i -= 49152;
  { int k = i>>7, n = i&127; baW1T[n*128+k] = f2b(aW1[i]); }
}

__global__ void hist_kernel(const int* __restrict__ dst, int* __restrict__ counts, int n){
  int i = blockIdx.x*blockDim.x + threadIdx.x; if (i<n) atomicAdd(&counts[dst[i]],1);
}
// parallel exclusive scan over counts -> rowp/cursor (3 phases)
__global__ void scanA_kernel(const int* __restrict__ counts, int* __restrict__ rowp,
                             int* __restrict__ bsum, int n){
  __shared__ int buf[1024];
  const int gid = blockIdx.x*1024 + threadIdx.x;
  int v = (gid<n) ? counts[gid] : 0;
  buf[threadIdx.x]=v; __syncthreads();
  for (int off=1; off<1024; off<<=1){
    int x = (threadIdx.x>=off) ? buf[threadIdx.x-off] : 0;
    __syncthreads();
    buf[threadIdx.x]+=x; __syncthreads();
  }
  if (gid<n) rowp[gid] = buf[threadIdx.x]-v;          // block-local exclusive
  if (threadIdx.x==1023) bsum[blockIdx.x]=buf[1023];  // block total
}
__global__ void scanB_kernel(int* bsum, int* rowp, int nb, int n){
  if (threadIdx.x==0 && blockIdx.x==0){
    int run=0;
    for (int b=0;b<nb;++b){ int t=bsum[b]; bsum[b]=run; run+=t; }
    rowp[n]=run;
  }
}
__global__ void scanC_kernel(int* __restrict__ rowp, int* __restrict__ cursor,
                             const int* __restrict__ bsum, int n){
  const int gid = blockIdx.x*1024 + threadIdx.x;
  if (gid<n){ int v = rowp[gid]+bsum[blockIdx.x]; rowp[gid]=v; cursor[gid]=v; }
}
__global__ void scatter_kernel(const int* __restrict__ dst, int* __restrict__ cursor,
                               int* __restrict__ eids, int n){
  int i = blockIdx.x*blockDim.x + threadIdx.x;
  if (i<n){ int p = atomicAdd(&cursor[dst[i]],1); eids[p]=i; }
}
// permuted edge endpoints (CSR order by dst)
__global__ void perm_kernel(const int* __restrict__ eids, const int* __restrict__ src,
                            const int* __restrict__ dst, int* __restrict__ srcp,
                            int* __restrict__ dstp, int n){
  int i = blockIdx.x*blockDim.x + threadIdx.x;
  if (i<n){ int e=eids[i]; srcp[i]=src[e]; dstp[i]=dst[e]; }
}
// gather+convert ef into permuted bf16 state
__global__ void efgather_kernel(const int* __restrict__ eids, const float* __restrict__ ef,
                                u16* __restrict__ efb){
  long i = (long)blockIdx.x*256 + threadIdx.x;   // NE*32 threads
  long pos = i>>5; int k4 = (int)(i&31);
  long e = eids[pos];
  float4 v = reinterpret_cast<const float4*>(ef + e*DIM)[k4];
  ushort4 o = { f2b(v.x), f2b(v.y), f2b(v.z), f2b(v.w) };
  reinterpret_cast<ushort4*>(efb + pos*DIM)[k4] = o;
}

// ---------- edge GRU + attention MLP (v13: 32-col mega-chunks, 10 barriers) ----------
// 512 thr = 8 waves x 16 edges. Mega-chunk = 32 output cols = 72 frags = 72KB
// single buffer -> 4 GRU mega-chunks + attn: 10 barriers (v12: 18). Halves the
// per-kernel drain events while doubling the MFMA block (72) between them.
// Shared r/z accumulators (v8-validated: MFMA C-accumulate folds gi+gh) keep
// 8 accs + 48 A-frag VGPRs under the (512,4)=128 cap -- occupancy must come
// from LDS, never the VGPR cap (v3/v6 remat). Stage pointers hoisted: 9
// per-wave pointers computed once, advanced by a constant per mega-chunk.
// SENTINEL: FETCH ~165MB; a blow-up means remat -> revert chunk size.
__global__ __launch_bounds__(512, 4)
void edge_kernel(const int* __restrict__ srcp, const int* __restrict__ dstp,
                 const int* __restrict__ eids,
                 const u16* __restrict__ nfb, u16* __restrict__ efb,
                 const u16* __restrict__ Wih, const u16* __restrict__ Whh,
                 const float* __restrict__ bih, const float* __restrict__ bhh,
                 const u16* __restrict__ aW1T, const float* __restrict__ ab1,
                 const float* __restrict__ aW2, const float* __restrict__ ab2,
                 float* __restrict__ logits, float* __restrict__ ef32out)
{
  __shared__ __align__(16) u16 wbuf[72*512];   // 72 KB, frag-major
  const int wave = threadIdx.x>>6, lane = threadIdx.x&63;
  const int r16 = lane&15, kq = lane>>4;
  const long base = (long)blockIdx.x*128 + wave*16;
  const long e = base + r16;

  // hoisted stage pointers: frag f = wave + 8k covers 0..71 across 8 waves.
  // half h=f/36 -> old 16-col chunk c = 2C+h; advance per mega-chunk = 32 rows.
  const u16* pk[9];
  int adv[9];
#pragma unroll
  for (int k=0;k<9;++k){
    const int f = wave + k*8;
    const int h = (f>=36) ? 1 : 0;
    const int ff = f - h*36;
    if (ff < 24){
      const int gt = ff>>3, s = ff&7;
      pk[k] = Wih + (long)(gt*128 + h*16 + r16)*256 + s*32 + kq*8;
      adv[k] = 32*256;
    } else {
      const int q = ff-24, gt = q>>2, s = q&3;
      pk[k] = Whh + (long)(gt*128 + h*16 + r16)*128 + s*32 + kq*8;
      adv[k] = 32*128;
    }
  }
  auto stageC = [&](){
#pragma unroll
    for (int k=0;k<9;++k){
      GLOAD_LDS(pk[k], wbuf + (wave + k*8)*512);
      pk[k] += adv[k];
    }
  };
  auto stageAttn = [&](){
#pragma unroll
    for (int k=0;k<4;++k){
      const int f = wave + k*8;          // 0..31
      const int t = f>>2, s = f&3;
      GLOAD_LDS(aW1T + (long)(t*16 + r16)*128 + s*32 + kq*8, wbuf + f*512);
    }
  };

  // A-fragments, loaded ONCE into registers: gi K=256 (src|dst), gh K=128 (ef)
  const u16* sp = nfb + (long)srcp[e]*DIM;
  const u16* dp = nfb + (long)dstp[e]*DIM;
  const u16* ep = efb + e*DIM;
  bf16x8 ag[8], ae[4];
#pragma unroll
  for (int s=0;s<4;++s){
    ag[s]   = ldb8(sp + s*32 + kq*8);
    ag[s+4] = ldb8(dp + s*32 + kq*8);
    ae[s]   = ldb8(ep + s*32 + kq*8);
  }
  // original edge ids for the 4 rows this lane epilogues (fp32 scatter on it1)
  int oe[4];
#pragma unroll
  for (int r=0;r<4;++r) oe[r] = eids[base + kq*4 + r];

  stageC();
  __syncthreads();

  u16* ebase = efb + (base + kq*4)*DIM + r16;
  const float* bi0 = bih + r16;
  const float* bh0 = bhh + r16;

  const f32x4 vzero = {0.f,0.f,0.f,0.f};
  const u16* lbase = wbuf + lane*8;   // frag f => lbase + f*512 (u16 units)

#pragma unroll 1
  for (int C=0;C<4;++C){
    const int c32 = C*32;
    float h0p[2][4];
#pragma unroll
    for (int h2=0;h2<2;++h2)
#pragma unroll
      for (int r=0;r<4;++r) h0p[h2][r] = b2f(ebase[r*DIM + c32 + h2*16]);

    f32x4 aR[2],aZ[2],aNi[2],aNh[2];
#pragma unroll
    for (int h2=0;h2<2;++h2){ aR[h2]=vzero; aZ[h2]=vzero; aNi[h2]=vzero; aNh[h2]=vzero; }
#pragma unroll
    for (int h2=0;h2<2;++h2){
      const u16* lb = lbase + h2*36*512;
#pragma unroll
      for (int s=0;s<8;++s){
        aR[h2]  = MFMA16(ag[s], ldb8(lb + ( s   )*512), aR[h2] ,0,0,0);
        aZ[h2]  = MFMA16(ag[s], ldb8(lb + ( 8+s )*512), aZ[h2] ,0,0,0);
        aNi[h2] = MFMA16(ag[s], ldb8(lb + (16+s )*512), aNi[h2],0,0,0);
      }
#pragma unroll
      for (int s=0;s<4;++s){
        aR[h2]  = MFMA16(ae[s], ldb8(lb + (24+s)*512), aR[h2] ,0,0,0);
        aZ[h2]  = MFMA16(ae[s], ldb8(lb + (28+s)*512), aZ[h2] ,0,0,0);
        aNh[h2] = MFMA16(ae[s], ldb8(lb + (32+s)*512), aNh[h2],0,0,0);
      }
    }
    __syncthreads();              // all waves done reading wbuf
    if (C < 3) stageC(); else stageAttn();   // refill; drains at end barrier
#pragma unroll
    for (int h2=0;h2<2;++h2){
      const int c16 = c32 + h2*16;
      const float btR = bi0[c16]       + bh0[c16];
      const float btZ = bi0[c16+DIM]   + bh0[c16+DIM];
      const float bin = bi0[c16+2*DIM];
      const float bhn = bh0[c16+2*DIM];
      float uv[4];
#pragma unroll
      for (int r=0;r<4;++r){
        float rg = sigm(aR[h2][r] + btR);
        float zg = sigm(aZ[h2][r] + btZ);
        float ng = tanh_(aNi[h2][r] + bin + rg*(aNh[h2][r] + bhn));
        float u  = ng + zg*(h0p[h2][r]-ng);
        ebase[r*DIM + c16] = f2b(u);
        uv[r] = u;
      }
      if (ef32out){
#pragma unroll
        for (int r=0;r<4;++r) ef32out[(long)oe[r]*DIM + c16 + r16] = uv[r];
      }
    }
    __syncthreads();              // wbuf refilled; stores drained
  }

  // ----- attention MLP: aW1T in wbuf frags 0..31; uef row re-read L1-hot -----
  bf16x8 ua[4];
#pragma unroll
  for (int s=0;s<4;++s) ua[s] = ldb8(ep + s*32 + kq*8);
  float part[4] = {0.f,0.f,0.f,0.f};
#pragma unroll 1
  for (int t=0;t<8;++t){
    f32x4 h = vzero;
#pragma unroll
    for (int s=0;s<4;++s)
      h = MFMA16(ua[s], ldb8(lbase + (t*4+s)*512), h,0,0,0);
    const int cc = t*16 + r16;
    const float b1 = ab1[cc], w2 = aW2[cc];
#pragma unroll
    for (int r=0;r<4;++r) part[r] += fmaxf(h[r]+b1, 0.f)*w2;
  }
#pragma unroll
  for (int off=1; off<16; off<<=1){
#pragma unroll
    for (int r=0;r<4;++r) part[r] += __shfl_xor(part[r], off, 64);
  }
  if (r16==0){
    const float b2v = ab2[0];
#pragma unroll
    for (int r=0;r<4;++r) logits[base + kq*4 + r] = part[r] + b2v;   // sequential
  }
}

// ---------- softmax + weighted aggregation (permuted CSR: fully sequential) ----------
__global__ __launch_bounds__(256)
void agg_kernel(const int* __restrict__ rowp, const float* __restrict__ logits,
                const u16* __restrict__ uefb, u16* __restrict__ aggb)
{
  const int wave = threadIdx.x>>6, lane = threadIdx.x&63;
  const int v = blockIdx.x*4 + wave;
  if (v>=NN) return;
  const int p0 = rowp[v], p1 = rowp[v+1], deg = p1-p0;
  float ax=0.f, ay=0.f;
  if (deg>0){
    float mx = -__builtin_inff();
    for (int i=p0+lane; i<p1; i+=64) mx = fmaxf(mx, logits[i]);
#pragma unroll
    for (int off=32; off; off>>=1) mx = fmaxf(mx, __shfl_xor(mx, off, 64));
    float ss = 0.f;
    for (int i=p0+lane; i<p1; i+=64) ss += __expf(logits[i] - mx);
#pragma unroll
    for (int off=32; off; off>>=1) ss += __shfl_xor(ss, off, 64);
    const float inv = 1.0f/ss;
    int i = p0;
    for (; i+2<=p1; i+=2){
      const float l0 = logits[i], l1 = logits[i+1];
      const unsigned q0 = *reinterpret_cast<const unsigned*>(uefb + (long)i*DIM + lane*2);
      const unsigned q1 = *reinterpret_cast<const unsigned*>(uefb + (long)(i+1)*DIM + lane*2);
      const float a0 = __expf(l0-mx)*inv, a1 = __expf(l1-mx)*inv;
      ax += a0*b2f((u16)q0) + a1*b2f((u16)q1);
      ay += a0*b2f((u16)(q0>>16)) + a1*b2f((u16)(q1>>16));
    }
    if (i<p1){
      const float a0 = __expf(logits[i]-mx)*inv;
      const unsigned q0 = *reinterpret_cast<const unsigned*>(uefb + (long)i*DIM + lane*2);
      ax += a0*b2f((u16)q0);
      ay += a0*b2f((u16)(q0>>16));
    }
  }
  unsigned pack = (unsigned)f2b(ax) | ((unsigned)f2b(ay)<<16);
  *reinterpret_cast<unsigned*>(aggb + (long)v*DIM + lane*2) = pack;
}

// ---------- node GRU (double-buffered staged weights, 8 waves x 16 nodes) ----------
__global__ __launch_bounds__(512, 4)
void node_kernel(const u16* __restrict__ aggb, u16* __restrict__ nfb,
                 const float* nf32, float* unf32,            // may alias (in-place iter 2)
                 const u16* __restrict__ Wih, const u16* __restrict__ Whh,
                 const float* __restrict__ bih, const float* __restrict__ bhh)
{
  __shared__ __align__(16) u16 wbuf[2*24*512];   // 48 KB, frag-major, double-buffered
  const int wave = threadIdx.x>>6, lane = threadIdx.x&63;
  const int r16 = lane&15, kq = lane>>4;
  const long tbase = (long)blockIdx.x*128 + wave*16;
  const long v = tbase + r16;
  const long vcl = (v < NN) ? v : (NN-1);

  auto stage = [&](int c){
    if (c >= 8) return;
    u16* bufp = wbuf + (c&1)*24*512;
    for (int f = wave; f < 24; f += 8){
      const u16* g;
      if (f < 12){ const int gt = f>>2, s = f&3;
        g = Wih + (long)(gt*128 + c*16 + r16)*128 + s*32 + kq*8; }
      else { const int q = f-12, gt = q>>2, s = q&3;
        g = Whh + (long)(gt*128 + c*16 + r16)*128 + s*32 + kq*8; }
      GLOAD_LDS(g, bufp + f*512);
    }
  };

  bf16x8 xa[4], ha[4];
#pragma unroll
  for (int s=0;s<4;++s){
    xa[s] = ldb8(aggb + vcl*DIM + s*32 + kq*8);
    ha[s] = ldb8(nfb  + vcl*DIM + s*32 + kq*8);
  }
  stage(0);
  __syncthreads();

  const f32x4 vzero = {0.f,0.f,0.f,0.f};

#pragma unroll 1
  for (int c=0;c<8;++c){
    stage(c+1);
    const int oc = c*16 + r16;
    const float bir=bih[oc], biz=bih[DIM+oc], bin=bih[2*DIM+oc];
    const float bhr=bhh[oc], bhz=bhh[DIM+oc], bhn=bhh[2*DIM+oc];
    float h0p[4];
#pragma unroll
    for (int r=0;r<4;++r){
      const long rr = tbase + kq*4 + r;
      h0p[r] = (rr < NN) ? nf32[rr*DIM+oc] : 0.f;
    }
    const u16* lb = wbuf + (c&1)*24*512 + lane*8;
    f32x4 ar=vzero, az=vzero, an=vzero, hr=vzero, hz=vzero, hn=vzero;
#pragma unroll
    for (int s=0;s<4;++s){
      ar=MFMA16(xa[s], ldb8(lb + ( s   )*512), ar,0,0,0);
      az=MFMA16(xa[s], ldb8(lb + ( 4+s)*512), az,0,0,0);
      an=MFMA16(xa[s], ldb8(lb + ( 8+s)*512), an,0,0,0);
      hr=MFMA16(ha[s], ldb8(lb + (12+s)*512), hr,0,0,0);
      hz=MFMA16(ha[s], ldb8(lb + (16+s)*512), hz,0,0,0);
      hn=MFMA16(ha[s], ldb8(lb + (20+s)*512), hn,0,0,0);
    }
#pragma unroll
    for (int r=0;r<4;++r){
      const long rr = tbase + kq*4 + r;
      if (rr < NN){
        float rg = sigm(ar[r]+bir + hr[r]+bhr);
        float zg = sigm(az[r]+biz + hz[r]+bhz);
        float ng = tanh_(an[r]+bin + rg*(hn[r]+bhn));
        float u  = ng + zg*(h0p[r]-ng);
        unf32[rr*DIM+oc] = u;
        nfb[rr*DIM+oc] = f2b(u);   // safe: nfb reads preloaded before loop
      }
    }
    __syncthreads();
  }
}

extern "C" void kernel_launch(void* const* d_in, const int* in_sizes, int n_in,
                              void* d_out, int out_size, void* d_ws, size_t ws_size,
                              hipStream_t stream)
{
  const float* nf_in = (const float*)d_in[0];
  const float* ef_in = (const float*)d_in[1];
  const int*   src   = (const int*)d_in[2];
  const int*   dst   = (const int*)d_in[3];
  const float* eWih  = (const float*)d_in[4];
  const float* eWhh  = (const float*)d_in[5];
  const float* ebih  = (const float*)d_in[6];
  const float* ebhh  = (const float*)d_in[7];
  const float* nWih  = (const float*)d_in[8];
  const float* nWhh  = (const float*)d_in[9];
  const float* nbih  = (const float*)d_in[10];
  const float* nbhh  = (const float*)d_in[11];
  const float* aW1   = (const float*)d_in[12];
  const float* ab1   = (const float*)d_in[13];
  const float* aW2   = (const float*)d_in[14];
  const float* ab2   = (const float*)d_in[15];

  float* nf_out = (float*)d_out;
  float* ef_out = nf_out + (size_t)NN*DIM;

  // workspace carve (~135 MB)
  char* p = (char*)d_ws;
  auto carve = [&](size_t bytes)->void*{ void* r = (void*)p; p += (bytes + 255) & ~(size_t)255; return r; };
  u16* efb    = (u16*)carve((size_t)NE*DIM*2);      // permuted (CSR order) ef state
  u16* nfb    = (u16*)carve((size_t)NN*DIM*2);
  u16* aggb   = (u16*)carve((size_t)NN*DIM*2);
  float* logits = (float*)carve((size_t)NE*4);      // permuted order
  int* eids   = (int*)carve((size_t)NE*4);
  int* srcp   = (int*)carve((size_t)NE*4);
  int* dstp   = (int*)carve((size_t)NE*4);
  int* counts = (int*)carve((size_t)NN*4);
  int* rowp   = (int*)carve((size_t)(NN+1)*4);
  int* cursor = (int*)carve((size_t)NN*4);
  int* bsum   = (int*)carve((size_t)64*4);
  u16* bWih   = (u16*)carve((size_t)384*256*2);
  u16* bWhh   = (u16*)carve((size_t)384*128*2);
  u16* bnWih  = (u16*)carve((size_t)384*128*2);
  u16* bnWhh  = (u16*)carve((size_t)384*128*2);
  u16* baW1T  = (u16*)carve((size_t)128*128*2);

  const int NB = (NN + 1023)/1024;   // 49 scan blocks

  // CSR over dst + permutation (constant across iterations)
  hipMemsetAsync(counts, 0, (size_t)NN*4, stream);
  hist_kernel<<<(NE+255)/256,256,0,stream>>>(dst, counts, NE);
  scanA_kernel<<<NB,1024,0,stream>>>(counts, rowp, bsum, NN);
  scanB_kernel<<<1,64,0,stream>>>(bsum, rowp, NB, NN);
  scanC_kernel<<<NB,1024,0,stream>>>(rowp, cursor, bsum, NN);
  scatter_kernel<<<(NE+255)/256,256,0,stream>>>(dst, cursor, eids, NE);
  perm_kernel<<<(NE+255)/256,256,0,stream>>>(eids, src, dst, srcp, dstp, NE);

  // bf16 conversions (once per launch); ef converted via permute-gather
  f2b_kernel<<<2048,256,0,stream>>>(nf_in, nfb, NN*DIM/4);
  efgather_kernel<<<NE*32/256,256,0,stream>>>(eids, ef_in, efb);
  wprep_kernel<<<1024,256,0,stream>>>(eWih, eWhh, nWih, nWhh, aW1,
                                      bWih, bWhh, bnWih, bnWhh, baW1T);

  for (int it=0; it<2; ++it){
    const float* nf_cur = (it==0) ? nf_in : nf_out;
    float* efout32 = (it==1) ? ef_out : nullptr;
    edge_kernel<<<NE/128,512,0,stream>>>(srcp, dstp, eids, nfb, efb,
                                         bWih, bWhh, ebih, ebhh,
                                         baW1T, ab1, aW2, ab2, logits, efout32);
    agg_kernel<<<(NN+3)/4,256,0,stream>>>(rowp, logits, efb, aggb);
    node_kernel<<<(NN+127)/128,512,0,stream>>>(aggb, nfb, nf_cur, nf_out,
                                               bnWih, bnWhh, nbih, nbhh);
  }
}

// Round 14
// 960.803 us; speedup vs baseline: 1.2428x; 1.2428x over previous
//
#include <hip/hip_runtime.h>

#define NN 50000
#define NE 400000
#define DIM 128

typedef __bf16 bf16x8 __attribute__((ext_vector_type(8)));
typedef float f32x4 __attribute__((ext_vector_type(4)));
typedef unsigned short u16;

#define MFMA16 __builtin_amdgcn_mfma_f32_16x16x32_bf16

__device__ __forceinline__ u16 f2b(float f){ __bf16 b=(__bf16)f; return __builtin_bit_cast(u16,b); }
__device__ __forceinline__ float b2f(u16 h){ unsigned u = ((unsigned)h)<<16; return __builtin_bit_cast(float,u); }
__device__ __forceinline__ float sigm(float x){ return 1.0f/(1.0f+__expf(-x)); }
__device__ __forceinline__ float tanh_(float x){ float e=__expf(2.0f*x); return 1.0f-2.0f/(e+1.0f); }
__device__ __forceinline__ bf16x8 ldb8(const u16* p){ return *reinterpret_cast<const bf16x8*>(p); }

#define GLOAD_LDS(gp, lp) __builtin_amdgcn_global_load_lds( \
    (const __attribute__((address_space(1))) void*)(gp),    \
    (__attribute__((address_space(3))) void*)(lp), 16, 0, 0)

// ---------- utility kernels ----------
__global__ void f2b_kernel(const float* __restrict__ in, u16* __restrict__ out, int n4){
  int i = blockIdx.x*blockDim.x + threadIdx.x;
  int st = gridDim.x*blockDim.x;
  for (; i<n4; i+=st){
    float4 v = reinterpret_cast<const float4*>(in)[i];
    ushort4 o = { f2b(v.x), f2b(v.y), f2b(v.z), f2b(v.w) };
    reinterpret_cast<ushort4*>(out)[i] = o;
  }
}

// fused weight prep: all 4 GRU weight converts + aW1 transpose in one launch
__global__ void wprep_kernel(const float* __restrict__ eWih, const float* __restrict__ eWhh,
                             const float* __restrict__ nWih, const float* __restrict__ nWhh,
                             const float* __restrict__ aW1,
                             u16* __restrict__ bWih, u16* __restrict__ bWhh,
                             u16* __restrict__ bnWih, u16* __restrict__ bnWhh,
                             u16* __restrict__ baW1T){
  int i = blockIdx.x*256 + threadIdx.x;        // 1024 blocks x 256 = 262144
  if (i < 98304){ bWih[i] = f2b(eWih[i]); return; }
  i -= 98304;
  if (i < 49152){ bWhh[i] = f2b(eWhh[i]); return; }
  i -= 49152;
  if (i < 49152){ bnWih[i] = f2b(nWih[i]); return; }
  i -= 49152;
  if (i < 49152){ bnWhh[i] = f2b(nWhh[i]); return; }
  i -= 49152;
  { int k = i>>7, n = i&127; baW1T[n*128+k] = f2b(aW1[i]); }
}

__global__ void hist_kernel(const int* __restrict__ dst, int* __restrict__ counts, int n){
  int i = blockIdx.x*blockDim.x + threadIdx.x; if (i<n) atomicAdd(&counts[dst[i]],1);
}
// parallel exclusive scan over counts -> rowp/cursor (3 phases)
__global__ void scanA_kernel(const int* __restrict__ counts, int* __restrict__ rowp,
                             int* __restrict__ bsum, int n){
  __shared__ int buf[1024];
  const int gid = blockIdx.x*1024 + threadIdx.x;
  int v = (gid<n) ? counts[gid] : 0;
  buf[threadIdx.x]=v; __syncthreads();
  for (int off=1; off<1024; off<<=1){
    int x = (threadIdx.x>=off) ? buf[threadIdx.x-off] : 0;
    __syncthreads();
    buf[threadIdx.x]+=x; __syncthreads();
  }
  if (gid<n) rowp[gid] = buf[threadIdx.x]-v;          // block-local exclusive
  if (threadIdx.x==1023) bsum[blockIdx.x]=buf[1023];  // block total
}
__global__ void scanB_kernel(int* bsum, int* rowp, int nb, int n){
  if (threadIdx.x==0 && blockIdx.x==0){
    int run=0;
    for (int b=0;b<nb;++b){ int t=bsum[b]; bsum[b]=run; run+=t; }
    rowp[n]=run;
  }
}
__global__ void scanC_kernel(int* __restrict__ rowp, int* __restrict__ cursor,
                             const int* __restrict__ bsum, int n){
  const int gid = blockIdx.x*1024 + threadIdx.x;
  if (gid<n){ int v = rowp[gid]+bsum[blockIdx.x]; rowp[gid]=v; cursor[gid]=v; }
}
__global__ void scatter_kernel(const int* __restrict__ dst, int* __restrict__ cursor,
                               int* __restrict__ eids, int n){
  int i = blockIdx.x*blockDim.x + threadIdx.x;
  if (i<n){ int p = atomicAdd(&cursor[dst[i]],1); eids[p]=i; }
}
// permuted edge endpoints (CSR order by dst)
__global__ void perm_kernel(const int* __restrict__ eids, const int* __restrict__ src,
                            const int* __restrict__ dst, int* __restrict__ srcp,
                            int* __restrict__ dstp, int n){
  int i = blockIdx.x*blockDim.x + threadIdx.x;
  if (i<n){ int e=eids[i]; srcp[i]=src[e]; dstp[i]=dst[e]; }
}
// gather+convert ef into permuted bf16 state
__global__ void efgather_kernel(const int* __restrict__ eids, const float* __restrict__ ef,
                                u16* __restrict__ efb){
  long i = (long)blockIdx.x*256 + threadIdx.x;   // NE*32 threads
  long pos = i>>5; int k4 = (int)(i&31);
  long e = eids[pos];
  float4 v = reinterpret_cast<const float4*>(ef + e*DIM)[k4];
  ushort4 o = { f2b(v.x), f2b(v.y), f2b(v.z), f2b(v.w) };
  reinterpret_cast<ushort4*>(efb + pos*DIM)[k4] = o;
}

// ---------- edge GRU + attention MLP (v14: 4-wave blocks, 4 barrier groups/CU) ----------
// v12 hot-loop verbatim, but 256 thr = 4 waves x 16 edges = 64 edges/block.
// Occupancy model (v3/v6/v7/v8/v13 fit): waves/SIMD = 256/VGPR -> VGPR 60 gives
// 16 waves/CU regardless of block size. At 512-thr that is TWO 8-wave barrier
// groups; at 256-thr it is FOUR 4-wave groups -> barrier drains in one group
// overlap compute in three others. LDS 36.9KB and VGPR ~60 both allow 4
// blocks/CU. Stage strides f+=4 (9 frags/wave GRU, 8 attn).
// SENTINEL: VGPR must stay ~60 and FETCH ~165MB (remat disease watch).
__global__ __launch_bounds__(256, 4)
void edge_kernel(const int* __restrict__ srcp, const int* __restrict__ dstp,
                 const int* __restrict__ eids,
                 const u16* __restrict__ nfb, u16* __restrict__ efb,
                 const u16* __restrict__ Wih, const u16* __restrict__ Whh,
                 const float* __restrict__ bih, const float* __restrict__ bhh,
                 const u16* __restrict__ aW1T, const float* __restrict__ ab1,
                 const float* __restrict__ aW2, const float* __restrict__ ab2,
                 float* __restrict__ logits, float* __restrict__ ef32out)
{
  __shared__ __align__(16) u16 wbuf[36*512];   // 36 KB, frag-major
  const int wave = threadIdx.x>>6, lane = threadIdx.x&63;
  const int r16 = lane&15, kq = lane>>4;
  const long base = (long)blockIdx.x*64 + wave*16;
  const long e = base + r16;

  // cooperative staging of chunk c's weight frags (c=8 -> attention weights)
  auto stage = [&](int c){
    if (c < 8){
      for (int f = wave; f < 36; f += 4){
        const u16* g;
        if (f < 24){ const int gt = f>>3, s = f&7;
          g = Wih + (long)(gt*128 + c*16 + r16)*256 + s*32 + kq*8; }
        else { const int q = f-24, gt = q>>2, s = q&3;
          g = Whh + (long)(gt*128 + c*16 + r16)*128 + s*32 + kq*8; }
        GLOAD_LDS(g, wbuf + f*512);
      }
    } else {
      for (int f = wave; f < 32; f += 4){
        const int t = f>>2, s = f&3;
        GLOAD_LDS(aW1T + (long)(t*16 + r16)*128 + s*32 + kq*8, wbuf + f*512);
      }
    }
  };

  // A-fragments, loaded ONCE into registers: gi K=256 (src|dst), gh K=128 (ef)
  const u16* sp = nfb + (long)srcp[e]*DIM;
  const u16* dp = nfb + (long)dstp[e]*DIM;
  const u16* ep = efb + e*DIM;
  bf16x8 ag[8], ae[4];
#pragma unroll
  for (int s=0;s<4;++s){
    ag[s]   = ldb8(sp + s*32 + kq*8);
    ag[s+4] = ldb8(dp + s*32 + kq*8);
    ae[s]   = ldb8(ep + s*32 + kq*8);
  }
  // original edge ids for the 4 rows this lane epilogues (fp32 scatter on it1)
  int oe[4];
#pragma unroll
  for (int r=0;r<4;++r) oe[r] = eids[base + kq*4 + r];

  stage(0);
  __syncthreads();

  // hoisted bases: all epilogue accesses are base + r*DIM + c*16 (imm-friendly)
  u16* ebase = efb + (base + kq*4)*DIM + r16;
  const float* bi0 = bih + r16;
  const float* bh0 = bhh + r16;

  const f32x4 vzero = {0.f,0.f,0.f,0.f};
  const u16* lbase = wbuf + lane*8;   // frag f => lbase + f*512 (u16 units)

#pragma unroll 1
  for (int c=0;c<8;++c){
    const int c16 = c*16;
    const float bir=bi0[c16], biz=bi0[c16+DIM], bin=bi0[c16+2*DIM];
    const float bhr=bh0[c16], bhz=bh0[c16+DIM], bhn=bh0[c16+2*DIM];
    float h0p[4];
#pragma unroll
    for (int r=0;r<4;++r) h0p[r] = b2f(ebase[r*DIM + c16]);  // L1/L2-hot

    f32x4 ar=vzero, az=vzero, an=vzero, hr=vzero, hz=vzero, hn=vzero;
#pragma unroll
    for (int s=0;s<8;++s){
      ar = MFMA16(ag[s], ldb8(lbase + ( s   )*512), ar,0,0,0);
      az = MFMA16(ag[s], ldb8(lbase + ( 8+s )*512), az,0,0,0);
      an = MFMA16(ag[s], ldb8(lbase + (16+s )*512), an,0,0,0);
    }
#pragma unroll
    for (int s=0;s<4;++s){
      hr = MFMA16(ae[s], ldb8(lbase + (24+s)*512), hr,0,0,0);
      hz = MFMA16(ae[s], ldb8(lbase + (28+s)*512), hz,0,0,0);
      hn = MFMA16(ae[s], ldb8(lbase + (32+s)*512), hn,0,0,0);
    }
    __syncthreads();              // all waves done reading wbuf
    stage(c+1);                   // refill; drains at end-of-chunk barrier
    float uv[4];
#pragma unroll
    for (int r=0;r<4;++r){
      float rg = sigm(ar[r]+bir + hr[r]+bhr);
      float zg = sigm(az[r]+biz + hz[r]+bhz);
      float ng = tanh_(an[r]+bin + rg*(hn[r]+bhn));
      float u  = ng + zg*(h0p[r]-ng);
      ebase[r*DIM + c16] = f2b(u);
      uv[r] = u;
    }
    if (ef32out){
#pragma unroll
      for (int r=0;r<4;++r) ef32out[(long)oe[r]*DIM + c16 + r16] = uv[r];
    }
    __syncthreads();              // wbuf refilled; stores drained
  }

  // ----- attention MLP: chunk 8 (aW1T) in wbuf; uef row re-read L1-hot -----
  bf16x8 ua[4];
#pragma unroll
  for (int s=0;s<4;++s) ua[s] = ldb8(ep + s*32 + kq*8);
  float part[4] = {0.f,0.f,0.f,0.f};
#pragma unroll 1
  for (int t=0;t<8;++t){
    f32x4 h = vzero;
#pragma unroll
    for (int s=0;s<4;++s)
      h = MFMA16(ua[s], ldb8(lbase + (t*4+s)*512), h,0,0,0);
    const int cc = t*16 + r16;
    const float b1 = ab1[cc], w2 = aW2[cc];
#pragma unroll
    for (int r=0;r<4;++r) part[r] += fmaxf(h[r]+b1, 0.f)*w2;
  }
#pragma unroll
  for (int off=1; off<16; off<<=1){
#pragma unroll
    for (int r=0;r<4;++r) part[r] += __shfl_xor(part[r], off, 64);
  }
  if (r16==0){
    const float b2v = ab2[0];
#pragma unroll
    for (int r=0;r<4;++r) logits[base + kq*4 + r] = part[r] + b2v;   // sequential
  }
}

// ---------- softmax + weighted aggregation (permuted CSR: fully sequential) ----------
__global__ __launch_bounds__(256)
void agg_kernel(const int* __restrict__ rowp, const float* __restrict__ logits,
                const u16* __restrict__ uefb, u16* __restrict__ aggb)
{
  const int wave = threadIdx.x>>6, lane = threadIdx.x&63;
  const int v = blockIdx.x*4 + wave;
  if (v>=NN) return;
  const int p0 = rowp[v], p1 = rowp[v+1], deg = p1-p0;
  float ax=0.f, ay=0.f;
  if (deg>0){
    float mx = -__builtin_inff();
    for (int i=p0+lane; i<p1; i+=64) mx = fmaxf(mx, logits[i]);
#pragma unroll
    for (int off=32; off; off>>=1) mx = fmaxf(mx, __shfl_xor(mx, off, 64));
    float ss = 0.f;
    for (int i=p0+lane; i<p1; i+=64) ss += __expf(logits[i] - mx);
#pragma unroll
    for (int off=32; off; off>>=1) ss += __shfl_xor(ss, off, 64);
    const float inv = 1.0f/ss;
    int i = p0;
    for (; i+2<=p1; i+=2){
      const float l0 = logits[i], l1 = logits[i+1];
      const unsigned q0 = *reinterpret_cast<const unsigned*>(uefb + (long)i*DIM + lane*2);
      const unsigned q1 = *reinterpret_cast<const unsigned*>(uefb + (long)(i+1)*DIM + lane*2);
      const float a0 = __expf(l0-mx)*inv, a1 = __expf(l1-mx)*inv;
      ax += a0*b2f((u16)q0) + a1*b2f((u16)q1);
      ay += a0*b2f((u16)(q0>>16)) + a1*b2f((u16)(q1>>16));
    }
    if (i<p1){
      const float a0 = __expf(logits[i]-mx)*inv;
      const unsigned q0 = *reinterpret_cast<const unsigned*>(uefb + (long)i*DIM + lane*2);
      ax += a0*b2f((u16)q0);
      ay += a0*b2f((u16)(q0>>16));
    }
  }
  unsigned pack = (unsigned)f2b(ax) | ((unsigned)f2b(ay)<<16);
  *reinterpret_cast<unsigned*>(aggb + (long)v*DIM + lane*2) = pack;
}

// ---------- node GRU (double-buffered staged weights, 8 waves x 16 nodes) ----------
__global__ __launch_bounds__(512, 4)
void node_kernel(const u16* __restrict__ aggb, u16* __restrict__ nfb,
                 const float* nf32, float* unf32,            // may alias (in-place iter 2)
                 const u16* __restrict__ Wih, const u16* __restrict__ Whh,
                 const float* __restrict__ bih, const float* __restrict__ bhh)
{
  __shared__ __align__(16) u16 wbuf[2*24*512];   // 48 KB, frag-major, double-buffered
  const int wave = threadIdx.x>>6, lane = threadIdx.x&63;
  const int r16 = lane&15, kq = lane>>4;
  const long tbase = (long)blockIdx.x*128 + wave*16;
  const long v = tbase + r16;
  const long vcl = (v < NN) ? v : (NN-1);

  auto stage = [&](int c){
    if (c >= 8) return;
    u16* bufp = wbuf + (c&1)*24*512;
    for (int f = wave; f < 24; f += 8){
      const u16* g;
      if (f < 12){ const int gt = f>>2, s = f&3;
        g = Wih + (long)(gt*128 + c*16 + r16)*128 + s*32 + kq*8; }
      else { const int q = f-12, gt = q>>2, s = q&3;
        g = Whh + (long)(gt*128 + c*16 + r16)*128 + s*32 + kq*8; }
      GLOAD_LDS(g, bufp + f*512);
    }
  };

  bf16x8 xa[4], ha[4];
#pragma unroll
  for (int s=0;s<4;++s){
    xa[s] = ldb8(aggb + vcl*DIM + s*32 + kq*8);
    ha[s] = ldb8(nfb  + vcl*DIM + s*32 + kq*8);
  }
  stage(0);
  __syncthreads();

  const f32x4 vzero = {0.f,0.f,0.f,0.f};

#pragma unroll 1
  for (int c=0;c<8;++c){
    stage(c+1);
    const int oc = c*16 + r16;
    const float bir=bih[oc], biz=bih[DIM+oc], bin=bih[2*DIM+oc];
    const float bhr=bhh[oc], bhz=bhh[DIM+oc], bhn=bhh[2*DIM+oc];
    float h0p[4];
#pragma unroll
    for (int r=0;r<4;++r){
      const long rr = tbase + kq*4 + r;
      h0p[r] = (rr < NN) ? nf32[rr*DIM+oc] : 0.f;
    }
    const u16* lb = wbuf + (c&1)*24*512 + lane*8;
    f32x4 ar=vzero, az=vzero, an=vzero, hr=vzero, hz=vzero, hn=vzero;
#pragma unroll
    for (int s=0;s<4;++s){
      ar=MFMA16(xa[s], ldb8(lb + ( s   )*512), ar,0,0,0);
      az=MFMA16(xa[s], ldb8(lb + ( 4+s)*512), az,0,0,0);
      an=MFMA16(xa[s], ldb8(lb + ( 8+s)*512), an,0,0,0);
      hr=MFMA16(ha[s], ldb8(lb + (12+s)*512), hr,0,0,0);
      hz=MFMA16(ha[s], ldb8(lb + (16+s)*512), hz,0,0,0);
      hn=MFMA16(ha[s], ldb8(lb + (20+s)*512), hn,0,0,0);
    }
#pragma unroll
    for (int r=0;r<4;++r){
      const long rr = tbase + kq*4 + r;
      if (rr < NN){
        float rg = sigm(ar[r]+bir + hr[r]+bhr);
        float zg = sigm(az[r]+biz + hz[r]+bhz);
        float ng = tanh_(an[r]+bin + rg*(hn[r]+bhn));
        float u  = ng + zg*(h0p[r]-ng);
        unf32[rr*DIM+oc] = u;
        nfb[rr*DIM+oc] = f2b(u);   // safe: nfb reads preloaded before loop
      }
    }
    __syncthreads();
  }
}

extern "C" void kernel_launch(void* const* d_in, const int* in_sizes, int n_in,
                              void* d_out, int out_size, void* d_ws, size_t ws_size,
                              hipStream_t stream)
{
  const float* nf_in = (const float*)d_in[0];
  const float* ef_in = (const float*)d_in[1];
  const int*   src   = (const int*)d_in[2];
  const int*   dst   = (const int*)d_in[3];
  const float* eWih  = (const float*)d_in[4];
  const float* eWhh  = (const float*)d_in[5];
  const float* ebih  = (const float*)d_in[6];
  const float* ebhh  = (const float*)d_in[7];
  const float* nWih  = (const float*)d_in[8];
  const float* nWhh  = (const float*)d_in[9];
  const float* nbih  = (const float*)d_in[10];
  const float* nbhh  = (const float*)d_in[11];
  const float* aW1   = (const float*)d_in[12];
  const float* ab1   = (const float*)d_in[13];
  const float* aW2   = (const float*)d_in[14];
  const float* ab2   = (const float*)d_in[15];

  float* nf_out = (float*)d_out;
  float* ef_out = nf_out + (size_t)NN*DIM;

  // workspace carve (~135 MB)
  char* p = (char*)d_ws;
  auto carve = [&](size_t bytes)->void*{ void* r = (void*)p; p += (bytes + 255) & ~(size_t)255; return r; };
  u16* efb    = (u16*)carve((size_t)NE*DIM*2);      // permuted (CSR order) ef state
  u16* nfb    = (u16*)carve((size_t)NN*DIM*2);
  u16* aggb   = (u16*)carve((size_t)NN*DIM*2);
  float* logits = (float*)carve((size_t)NE*4);      // permuted order
  int* eids   = (int*)carve((size_t)NE*4);
  int* srcp   = (int*)carve((size_t)NE*4);
  int* dstp   = (int*)carve((size_t)NE*4);
  int* counts = (int*)carve((size_t)NN*4);
  int* rowp   = (int*)carve((size_t)(NN+1)*4);
  int* cursor = (int*)carve((size_t)NN*4);
  int* bsum   = (int*)carve((size_t)64*4);
  u16* bWih   = (u16*)carve((size_t)384*256*2);
  u16* bWhh   = (u16*)carve((size_t)384*128*2);
  u16* bnWih  = (u16*)carve((size_t)384*128*2);
  u16* bnWhh  = (u16*)carve((size_t)384*128*2);
  u16* baW1T  = (u16*)carve((size_t)128*128*2);

  const int NB = (NN + 1023)/1024;   // 49 scan blocks

  // CSR over dst + permutation (constant across iterations)
  hipMemsetAsync(counts, 0, (size_t)NN*4, stream);
  hist_kernel<<<(NE+255)/256,256,0,stream>>>(dst, counts, NE);
  scanA_kernel<<<NB,1024,0,stream>>>(counts, rowp, bsum, NN);
  scanB_kernel<<<1,64,0,stream>>>(bsum, rowp, NB, NN);
  scanC_kernel<<<NB,1024,0,stream>>>(rowp, cursor, bsum, NN);
  scatter_kernel<<<(NE+255)/256,256,0,stream>>>(dst, cursor, eids, NE);
  perm_kernel<<<(NE+255)/256,256,0,stream>>>(eids, src, dst, srcp, dstp, NE);

  // bf16 conversions (once per launch); ef converted via permute-gather
  f2b_kernel<<<2048,256,0,stream>>>(nf_in, nfb, NN*DIM/4);
  efgather_kernel<<<NE*32/256,256,0,stream>>>(eids, ef_in, efb);
  wprep_kernel<<<1024,256,0,stream>>>(eWih, eWhh, nWih, nWhh, aW1,
                                      bWih, bWhh, bnWih, bnWhh, baW1T);

  for (int it=0; it<2; ++it){
    const float* nf_cur = (it==0) ? nf_in : nf_out;
    float* efout32 = (it==1) ? ef_out : nullptr;
    edge_kernel<<<NE/64,256,0,stream>>>(srcp, dstp, eids, nfb, efb,
                                        bWih, bWhh, ebih, ebhh,
                                        baW1T, ab1, aW2, ab2, logits, efout32);
    agg_kernel<<<(NN+3)/4,256,0,stream>>>(rowp, logits, efb, aggb);
    node_kernel<<<(NN+127)/128,512,0,stream>>>(aggb, nfb, nf_cur, nf_out,
                                               bnWih, bnWhh, nbih, nbhh);
  }
}

// Round 15
// 791.816 us; speedup vs baseline: 1.5080x; 1.2134x over previous
//
#include <hip/hip_runtime.h>

#define NN 50000
#define NE 400000
#define DIM 128

typedef __bf16 bf16x8 __attribute__((ext_vector_type(8)));
typedef float f32x4 __attribute__((ext_vector_type(4)));
typedef unsigned short u16;

#define MFMA16 __builtin_amdgcn_mfma_f32_16x16x32_bf16

__device__ __forceinline__ u16 f2b(float f){ __bf16 b=(__bf16)f; return __builtin_bit_cast(u16,b); }
__device__ __forceinline__ float b2f(u16 h){ unsigned u = ((unsigned)h)<<16; return __builtin_bit_cast(float,u); }
__device__ __forceinline__ float sigm(float x){ return 1.0f/(1.0f+__expf(-x)); }
__device__ __forceinline__ float tanh_(float x){ float e=__expf(2.0f*x); return 1.0f-2.0f/(e+1.0f); }
__device__ __forceinline__ bf16x8 ldb8(const u16* p){ return *reinterpret_cast<const bf16x8*>(p); }

#define GLOAD_LDS(gp, lp) __builtin_amdgcn_global_load_lds( \
    (const __attribute__((address_space(1))) void*)(gp),    \
    (__attribute__((address_space(3))) void*)(lp), 16, 0, 0)

// ---------- utility kernels ----------
__global__ void f2b_kernel(const float* __restrict__ in, u16* __restrict__ out, int n4){
  int i = blockIdx.x*blockDim.x + threadIdx.x;
  int st = gridDim.x*blockDim.x;
  for (; i<n4; i+=st){
    float4 v = reinterpret_cast<const float4*>(in)[i];
    ushort4 o = { f2b(v.x), f2b(v.y), f2b(v.z), f2b(v.w) };
    reinterpret_cast<ushort4*>(out)[i] = o;
  }
}

// fused weight prep: all 4 GRU weight converts + aW1 transpose in one launch
__global__ void wprep_kernel(const float* __restrict__ eWih, const float* __restrict__ eWhh,
                             const float* __restrict__ nWih, const float* __restrict__ nWhh,
                             const float* __restrict__ aW1,
                             u16* __restrict__ bWih, u16* __restrict__ bWhh,
                             u16* __restrict__ bnWih, u16* __restrict__ bnWhh,
                             u16* __restrict__ baW1T){
  int i = blockIdx.x*256 + threadIdx.x;        // 1024 blocks x 256 = 262144
  if (i < 98304){ bWih[i] = f2b(eWih[i]); return; }
  i -= 98304;
  if (i < 49152){ bWhh[i] = f2b(eWhh[i]); return; }
  i -= 49152;
  if (i < 49152){ bnWih[i] = f2b(nWih[i]); return; }
  i -= 49152;
  if (i < 49152){ bnWhh[i] = f2b(nWhh[i]); return; }
  i -= 49152;
  { int k = i>>7, n = i&127; baW1T[n*128+k] = f2b(aW1[i]); }
}

__global__ void hist_kernel(const int* __restrict__ dst, int* __restrict__ counts, int n){
  int i = blockIdx.x*blockDim.x + threadIdx.x; if (i<n) atomicAdd(&counts[dst[i]],1);
}
// parallel exclusive scan over counts -> rowp/cursor (3 phases)
__global__ void scanA_kernel(const int* __restrict__ counts, int* __restrict__ rowp,
                             int* __restrict__ bsum, int n){
  __shared__ int buf[1024];
  const int gid = blockIdx.x*1024 + threadIdx.x;
  int v = (gid<n) ? counts[gid] : 0;
  buf[threadIdx.x]=v; __syncthreads();
  for (int off=1; off<1024; off<<=1){
    int x = (threadIdx.x>=off) ? buf[threadIdx.x-off] : 0;
    __syncthreads();
    buf[threadIdx.x]+=x; __syncthreads();
  }
  if (gid<n) rowp[gid] = buf[threadIdx.x]-v;          // block-local exclusive
  if (threadIdx.x==1023) bsum[blockIdx.x]=buf[1023];  // block total
}
__global__ void scanB_kernel(int* bsum, int* rowp, int nb, int n){
  if (threadIdx.x==0 && blockIdx.x==0){
    int run=0;
    for (int b=0;b<nb;++b){ int t=bsum[b]; bsum[b]=run; run+=t; }
    rowp[n]=run;
  }
}
__global__ void scanC_kernel(int* __restrict__ rowp, int* __restrict__ cursor,
                             const int* __restrict__ bsum, int n){
  const int gid = blockIdx.x*1024 + threadIdx.x;
  if (gid<n){ int v = rowp[gid]+bsum[blockIdx.x]; rowp[gid]=v; cursor[gid]=v; }
}
__global__ void scatter_kernel(const int* __restrict__ dst, int* __restrict__ cursor,
                               int* __restrict__ eids, int n){
  int i = blockIdx.x*blockDim.x + threadIdx.x;
  if (i<n){ int p = atomicAdd(&cursor[dst[i]],1); eids[p]=i; }
}
// permuted edge endpoints (CSR order by dst)
__global__ void perm_kernel(const int* __restrict__ eids, const int* __restrict__ src,
                            const int* __restrict__ dst, int* __restrict__ srcp,
                            int* __restrict__ dstp, int n){
  int i = blockIdx.x*blockDim.x + threadIdx.x;
  if (i<n){ int e=eids[i]; srcp[i]=src[e]; dstp[i]=dst[e]; }
}
// gather+convert ef into permuted bf16 state
__global__ void efgather_kernel(const int* __restrict__ eids, const float* __restrict__ ef,
                                u16* __restrict__ efb){
  long i = (long)blockIdx.x*256 + threadIdx.x;   // NE*32 threads
  long pos = i>>5; int k4 = (int)(i&31);
  long e = eids[pos];
  float4 v = reinterpret_cast<const float4*>(ef + e*DIM)[k4];
  ushort4 o = { f2b(v.x), f2b(v.y), f2b(v.z), f2b(v.w) };
  reinterpret_cast<ushort4*>(efb + pos*DIM)[k4] = o;
}

// ---------- edge GRU + attention MLP (v15 == v12, the converged optimum) ----------
// 512 thr = 8 waves x 16 edges, single 36KB frag-major weight buffer
// (Wih+Whh staged per chunk; attn = chunk 8), 2-barrier chunk loop,
// launch_bounds(512,4) so A-frags stay in registers.
// Design-space closure (rounds 4-14): LDS 24/36/68/72KB, block 256/512,
// barriers 10/18, M=16/32, dbuf, L2-streamed B-frags, factored gi, atomic
// fusion -- every deviation from THIS point regresses. Constraints: VGPR<48
// impossible (A-frag residency), VGPR>=64 -> 16 waves/CU (waves/SIMD=256/VGPR),
// LDS-resident weights mandatory (v2/v11), barrier drains partially overlapped
// by ~2 co-resident blocks; residual is drain exposure + dependent-chain latency.
__global__ __launch_bounds__(512, 4)
void edge_kernel(const int* __restrict__ srcp, const int* __restrict__ dstp,
                 const int* __restrict__ eids,
                 const u16* __restrict__ nfb, u16* __restrict__ efb,
                 const u16* __restrict__ Wih, const u16* __restrict__ Whh,
                 const float* __restrict__ bih, const float* __restrict__ bhh,
                 const u16* __restrict__ aW1T, const float* __restrict__ ab1,
                 const float* __restrict__ aW2, const float* __restrict__ ab2,
                 float* __restrict__ logits, float* __restrict__ ef32out)
{
  __shared__ __align__(16) u16 wbuf[36*512];   // 36 KB, frag-major
  const int wave = threadIdx.x>>6, lane = threadIdx.x&63;
  const int r16 = lane&15, kq = lane>>4;
  const long base = (long)blockIdx.x*128 + wave*16;
  const long e = base + r16;

  // cooperative staging of chunk c's weight frags (c=8 -> attention weights)
  auto stage = [&](int c){
    if (c < 8){
      for (int f = wave; f < 36; f += 8){
        const u16* g;
        if (f < 24){ const int gt = f>>3, s = f&7;
          g = Wih + (long)(gt*128 + c*16 + r16)*256 + s*32 + kq*8; }
        else { const int q = f-24, gt = q>>2, s = q&3;
          g = Whh + (long)(gt*128 + c*16 + r16)*128 + s*32 + kq*8; }
        GLOAD_LDS(g, wbuf + f*512);
      }
    } else {
      for (int f = wave; f < 32; f += 8){
        const int t = f>>2, s = f&3;
        GLOAD_LDS(aW1T + (long)(t*16 + r16)*128 + s*32 + kq*8, wbuf + f*512);
      }
    }
  };

  // A-fragments, loaded ONCE into registers: gi K=256 (src|dst), gh K=128 (ef)
  const u16* sp = nfb + (long)srcp[e]*DIM;
  const u16* dp = nfb + (long)dstp[e]*DIM;
  const u16* ep = efb + e*DIM;
  bf16x8 ag[8], ae[4];
#pragma unroll
  for (int s=0;s<4;++s){
    ag[s]   = ldb8(sp + s*32 + kq*8);
    ag[s+4] = ldb8(dp + s*32 + kq*8);
    ae[s]   = ldb8(ep + s*32 + kq*8);
  }
  // original edge ids for the 4 rows this lane epilogues (fp32 scatter on it1)
  int oe[4];
#pragma unroll
  for (int r=0;r<4;++r) oe[r] = eids[base + kq*4 + r];

  stage(0);
  __syncthreads();

  // hoisted bases: all epilogue accesses are base + r*DIM + c*16 (imm-friendly)
  u16* ebase = efb + (base + kq*4)*DIM + r16;
  const float* bi0 = bih + r16;
  const float* bh0 = bhh + r16;

  const f32x4 vzero = {0.f,0.f,0.f,0.f};
  const u16* lbase = wbuf + lane*8;   // frag f => lbase + f*512 (u16 units)

#pragma unroll 1
  for (int c=0;c<8;++c){
    const int c16 = c*16;
    const float bir=bi0[c16], biz=bi0[c16+DIM], bin=bi0[c16+2*DIM];
    const float bhr=bh0[c16], bhz=bh0[c16+DIM], bhn=bh0[c16+2*DIM];
    float h0p[4];
#pragma unroll
    for (int r=0;r<4;++r) h0p[r] = b2f(ebase[r*DIM + c16]);  // L1/L2-hot

    f32x4 ar=vzero, az=vzero, an=vzero, hr=vzero, hz=vzero, hn=vzero;
#pragma unroll
    for (int s=0;s<8;++s){
      ar = MFMA16(ag[s], ldb8(lbase + ( s   )*512), ar,0,0,0);
      az = MFMA16(ag[s], ldb8(lbase + ( 8+s )*512), az,0,0,0);
      an = MFMA16(ag[s], ldb8(lbase + (16+s )*512), an,0,0,0);
    }
#pragma unroll
    for (int s=0;s<4;++s){
      hr = MFMA16(ae[s], ldb8(lbase + (24+s)*512), hr,0,0,0);
      hz = MFMA16(ae[s], ldb8(lbase + (28+s)*512), hz,0,0,0);
      hn = MFMA16(ae[s], ldb8(lbase + (32+s)*512), hn,0,0,0);
    }
    __syncthreads();              // all waves done reading wbuf
    stage(c+1);                   // refill; drains at end-of-chunk barrier
    float uv[4];
#pragma unroll
    for (int r=0;r<4;++r){
      float rg = sigm(ar[r]+bir + hr[r]+bhr);
      float zg = sigm(az[r]+biz + hz[r]+bhz);
      float ng = tanh_(an[r]+bin + rg*(hn[r]+bhn));
      float u  = ng + zg*(h0p[r]-ng);
      ebase[r*DIM + c16] = f2b(u);
      uv[r] = u;
    }
    if (ef32out){
#pragma unroll
      for (int r=0;r<4;++r) ef32out[(long)oe[r]*DIM + c16 + r16] = uv[r];
    }
    __syncthreads();              // wbuf refilled; stores drained
  }

  // ----- attention MLP: chunk 8 (aW1T) in wbuf; uef row re-read L1-hot -----
  bf16x8 ua[4];
#pragma unroll
  for (int s=0;s<4;++s) ua[s] = ldb8(ep + s*32 + kq*8);
  float part[4] = {0.f,0.f,0.f,0.f};
#pragma unroll 1
  for (int t=0;t<8;++t){
    f32x4 h = vzero;
#pragma unroll
    for (int s=0;s<4;++s)
      h = MFMA16(ua[s], ldb8(lbase + (t*4+s)*512), h,0,0,0);
    const int cc = t*16 + r16;
    const float b1 = ab1[cc], w2 = aW2[cc];
#pragma unroll
    for (int r=0;r<4;++r) part[r] += fmaxf(h[r]+b1, 0.f)*w2;
  }
#pragma unroll
  for (int off=1; off<16; off<<=1){
#pragma unroll
    for (int r=0;r<4;++r) part[r] += __shfl_xor(part[r], off, 64);
  }
  if (r16==0){
    const float b2v = ab2[0];
#pragma unroll
    for (int r=0;r<4;++r) logits[base + kq*4 + r] = part[r] + b2v;   // sequential
  }
}

// ---------- softmax + weighted aggregation (permuted CSR: fully sequential) ----------
__global__ __launch_bounds__(256)
void agg_kernel(const int* __restrict__ rowp, const float* __restrict__ logits,
                const u16* __restrict__ uefb, u16* __restrict__ aggb)
{
  const int wave = threadIdx.x>>6, lane = threadIdx.x&63;
  const int v = blockIdx.x*4 + wave;
  if (v>=NN) return;
  const int p0 = rowp[v], p1 = rowp[v+1], deg = p1-p0;
  float ax=0.f, ay=0.f;
  if (deg>0){
    float mx = -__builtin_inff();
    for (int i=p0+lane; i<p1; i+=64) mx = fmaxf(mx, logits[i]);
#pragma unroll
    for (int off=32; off; off>>=1) mx = fmaxf(mx, __shfl_xor(mx, off, 64));
    float ss = 0.f;
    for (int i=p0+lane; i<p1; i+=64) ss += __expf(logits[i] - mx);
#pragma unroll
    for (int off=32; off; off>>=1) ss += __shfl_xor(ss, off, 64);
    const float inv = 1.0f/ss;
    int i = p0;
    for (; i+2<=p1; i+=2){
      const float l0 = logits[i], l1 = logits[i+1];
      const unsigned q0 = *reinterpret_cast<const unsigned*>(uefb + (long)i*DIM + lane*2);
      const unsigned q1 = *reinterpret_cast<const unsigned*>(uefb + (long)(i+1)*DIM + lane*2);
      const float a0 = __expf(l0-mx)*inv, a1 = __expf(l1-mx)*inv;
      ax += a0*b2f((u16)q0) + a1*b2f((u16)q1);
      ay += a0*b2f((u16)(q0>>16)) + a1*b2f((u16)(q1>>16));
    }
    if (i<p1){
      const float a0 = __expf(logits[i]-mx)*inv;
      const unsigned q0 = *reinterpret_cast<const unsigned*>(uefb + (long)i*DIM + lane*2);
      ax += a0*b2f((u16)q0);
      ay += a0*b2f((u16)(q0>>16));
    }
  }
  unsigned pack = (unsigned)f2b(ax) | ((unsigned)f2b(ay)<<16);
  *reinterpret_cast<unsigned*>(aggb + (long)v*DIM + lane*2) = pack;
}

// ---------- node GRU (double-buffered staged weights, 8 waves x 16 nodes) ----------
__global__ __launch_bounds__(512, 4)
void node_kernel(const u16* __restrict__ aggb, u16* __restrict__ nfb,
                 const float* nf32, float* unf32,            // may alias (in-place iter 2)
                 const u16* __restrict__ Wih, const u16* __restrict__ Whh,
                 const float* __restrict__ bih, const float* __restrict__ bhh)
{
  __shared__ __align__(16) u16 wbuf[2*24*512];   // 48 KB, frag-major, double-buffered
  const int wave = threadIdx.x>>6, lane = threadIdx.x&63;
  const int r16 = lane&15, kq = lane>>4;
  const long tbase = (long)blockIdx.x*128 + wave*16;
  const long v = tbase + r16;
  const long vcl = (v < NN) ? v : (NN-1);

  auto stage = [&](int c){
    if (c >= 8) return;
    u16* bufp = wbuf + (c&1)*24*512;
    for (int f = wave; f < 24; f += 8){
      const u16* g;
      if (f < 12){ const int gt = f>>2, s = f&3;
        g = Wih + (long)(gt*128 + c*16 + r16)*128 + s*32 + kq*8; }
      else { const int q = f-12, gt = q>>2, s = q&3;
        g = Whh + (long)(gt*128 + c*16 + r16)*128 + s*32 + kq*8; }
      GLOAD_LDS(g, bufp + f*512);
    }
  };

  bf16x8 xa[4], ha[4];
#pragma unroll
  for (int s=0;s<4;++s){
    xa[s] = ldb8(aggb + vcl*DIM + s*32 + kq*8);
    ha[s] = ldb8(nfb  + vcl*DIM + s*32 + kq*8);
  }
  stage(0);
  __syncthreads();

  const f32x4 vzero = {0.f,0.f,0.f,0.f};

#pragma unroll 1
  for (int c=0;c<8;++c){
    stage(c+1);
    const int oc = c*16 + r16;
    const float bir=bih[oc], biz=bih[DIM+oc], bin=bih[2*DIM+oc];
    const float bhr=bhh[oc], bhz=bhh[DIM+oc], bhn=bhh[2*DIM+oc];
    float h0p[4];
#pragma unroll
    for (int r=0;r<4;++r){
      const long rr = tbase + kq*4 + r;
      h0p[r] = (rr < NN) ? nf32[rr*DIM+oc] : 0.f;
    }
    const u16* lb = wbuf + (c&1)*24*512 + lane*8;
    f32x4 ar=vzero, az=vzero, an=vzero, hr=vzero, hz=vzero, hn=vzero;
#pragma unroll
    for (int s=0;s<4;++s){
      ar=MFMA16(xa[s], ldb8(lb + ( s   )*512), ar,0,0,0);
      az=MFMA16(xa[s], ldb8(lb + ( 4+s)*512), az,0,0,0);
      an=MFMA16(xa[s], ldb8(lb + ( 8+s)*512), an,0,0,0);
      hr=MFMA16(ha[s], ldb8(lb + (12+s)*512), hr,0,0,0);
      hz=MFMA16(ha[s], ldb8(lb + (16+s)*512), hz,0,0,0);
      hn=MFMA16(ha[s], ldb8(lb + (20+s)*512), hn,0,0,0);
    }
#pragma unroll
    for (int r=0;r<4;++r){
      const long rr = tbase + kq*4 + r;
      if (rr < NN){
        float rg = sigm(ar[r]+bir + hr[r]+bhr);
        float zg = sigm(az[r]+biz + hz[r]+bhz);
        float ng = tanh_(an[r]+bin + rg*(hn[r]+bhn));
        float u  = ng + zg*(h0p[r]-ng);
        unf32[rr*DIM+oc] = u;
        nfb[rr*DIM+oc] = f2b(u);   // safe: nfb reads preloaded before loop
      }
    }
    __syncthreads();
  }
}

extern "C" void kernel_launch(void* const* d_in, const int* in_sizes, int n_in,
                              void* d_out, int out_size, void* d_ws, size_t ws_size,
                              hipStream_t stream)
{
  const float* nf_in = (const float*)d_in[0];
  const float* ef_in = (const float*)d_in[1];
  const int*   src   = (const int*)d_in[2];
  const int*   dst   = (const int*)d_in[3];
  const float* eWih  = (const float*)d_in[4];
  const float* eWhh  = (const float*)d_in[5];
  const float* ebih  = (const float*)d_in[6];
  const float* ebhh  = (const float*)d_in[7];
  const float* nWih  = (const float*)d_in[8];
  const float* nWhh  = (const float*)d_in[9];
  const float* nbih  = (const float*)d_in[10];
  const float* nbhh  = (const float*)d_in[11];
  const float* aW1   = (const float*)d_in[12];
  const float* ab1   = (const float*)d_in[13];
  const float* aW2   = (const float*)d_in[14];
  const float* ab2   = (const float*)d_in[15];

  float* nf_out = (float*)d_out;
  float* ef_out = nf_out + (size_t)NN*DIM;

  // workspace carve (~135 MB)
  char* p = (char*)d_ws;
  auto carve = [&](size_t bytes)->void*{ void* r = (void*)p; p += (bytes + 255) & ~(size_t)255; return r; };
  u16* efb    = (u16*)carve((size_t)NE*DIM*2);      // permuted (CSR order) ef state
  u16* nfb    = (u16*)carve((size_t)NN*DIM*2);
  u16* aggb   = (u16*)carve((size_t)NN*DIM*2);
  float* logits = (float*)carve((size_t)NE*4);      // permuted order
  int* eids   = (int*)carve((size_t)NE*4);
  int* srcp   = (int*)carve((size_t)NE*4);
  int* dstp   = (int*)carve((size_t)NE*4);
  int* counts = (int*)carve((size_t)NN*4);
  int* rowp   = (int*)carve((size_t)(NN+1)*4);
  int* cursor = (int*)carve((size_t)NN*4);
  int* bsum   = (int*)carve((size_t)64*4);
  u16* bWih   = (u16*)carve((size_t)384*256*2);
  u16* bWhh   = (u16*)carve((size_t)384*128*2);
  u16* bnWih  = (u16*)carve((size_t)384*128*2);
  u16* bnWhh  = (u16*)carve((size_t)384*128*2);
  u16* baW1T  = (u16*)carve((size_t)128*128*2);

  const int NB = (NN + 1023)/1024;   // 49 scan blocks

  // CSR over dst + permutation (constant across iterations)
  hipMemsetAsync(counts, 0, (size_t)NN*4, stream);
  hist_kernel<<<(NE+255)/256,256,0,stream>>>(dst, counts, NE);
  scanA_kernel<<<NB,1024,0,stream>>>(counts, rowp, bsum, NN);
  scanB_kernel<<<1,64,0,stream>>>(bsum, rowp, NB, NN);
  scanC_kernel<<<NB,1024,0,stream>>>(rowp, cursor, bsum, NN);
  scatter_kernel<<<(NE+255)/256,256,0,stream>>>(dst, cursor, eids, NE);
  perm_kernel<<<(NE+255)/256,256,0,stream>>>(eids, src, dst, srcp, dstp, NE);

  // bf16 conversions (once per launch); ef converted via permute-gather
  f2b_kernel<<<2048,256,0,stream>>>(nf_in, nfb, NN*DIM/4);
  efgather_kernel<<<NE*32/256,256,0,stream>>>(eids, ef_in, efb);
  wprep_kernel<<<1024,256,0,stream>>>(eWih, eWhh, nWih, nWhh, aW1,
                                      bWih, bWhh, bnWih, bnWhh, baW1T);

  for (int it=0; it<2; ++it){
    const float* nf_cur = (it==0) ? nf_in : nf_out;
    float* efout32 = (it==1) ? ef_out : nullptr;
    edge_kernel<<<NE/128,512,0,stream>>>(srcp, dstp, eids, nfb, efb,
                                         bWih, bWhh, ebih, ebhh,
                                         baW1T, ab1, aW2, ab2, logits, efout32);
    agg_kernel<<<(NN+3)/4,256,0,stream>>>(rowp, logits, efb, aggb);
    node_kernel<<<(NN+127)/128,512,0,stream>>>(aggb, nfb, nf_cur, nf_out,
                                               bnWih, bnWhh, nbih, nbhh);
  }
}

// Round 16
// 766.040 us; speedup vs baseline: 1.5588x; 1.0336x over previous
//
#include <hip/hip_runtime.h>

#define NN 50000
#define NE 400000
#define DIM 128

typedef __bf16 bf16x8 __attribute__((ext_vector_type(8)));
typedef float f32x4 __attribute__((ext_vector_type(4)));
typedef unsigned short u16;

#define MFMA16 __builtin_amdgcn_mfma_f32_16x16x32_bf16

__device__ __forceinline__ u16 f2b(float f){ __bf16 b=(__bf16)f; return __builtin_bit_cast(u16,b); }
__device__ __forceinline__ float b2f(u16 h){ unsigned u = ((unsigned)h)<<16; return __builtin_bit_cast(float,u); }
__device__ __forceinline__ float sigm(float x){ return 1.0f/(1.0f+__expf(-x)); }
__device__ __forceinline__ float tanh_(float x){ float e=__expf(2.0f*x); return 1.0f-2.0f/(e+1.0f); }
__device__ __forceinline__ bf16x8 ldb8(const u16* p){ return *reinterpret_cast<const bf16x8*>(p); }

#define GLOAD_LDS(gp, lp) __builtin_amdgcn_global_load_lds( \
    (const __attribute__((address_space(1))) void*)(gp),    \
    (__attribute__((address_space(3))) void*)(lp), 16, 0, 0)

// ---------- utility kernels ----------
__global__ void f2b_kernel(const float* __restrict__ in, u16* __restrict__ out, int n4){
  int i = blockIdx.x*blockDim.x + threadIdx.x;
  int st = gridDim.x*blockDim.x;
  for (; i<n4; i+=st){
    float4 v = reinterpret_cast<const float4*>(in)[i];
    ushort4 o = { f2b(v.x), f2b(v.y), f2b(v.z), f2b(v.w) };
    reinterpret_cast<ushort4*>(out)[i] = o;
  }
}

// fused weight prep: all 4 GRU weight converts + aW1 transpose in one launch
__global__ void wprep_kernel(const float* __restrict__ eWih, const float* __restrict__ eWhh,
                             const float* __restrict__ nWih, const float* __restrict__ nWhh,
                             const float* __restrict__ aW1,
                             u16* __restrict__ bWih, u16* __restrict__ bWhh,
                             u16* __restrict__ bnWih, u16* __restrict__ bnWhh,
                             u16* __restrict__ baW1T){
  int i = blockIdx.x*256 + threadIdx.x;        // 1024 blocks x 256 = 262144
  if (i < 98304){ bWih[i] = f2b(eWih[i]); return; }
  i -= 98304;
  if (i < 49152){ bWhh[i] = f2b(eWhh[i]); return; }
  i -= 49152;
  if (i < 49152){ bnWih[i] = f2b(nWih[i]); return; }
  i -= 49152;
  if (i < 49152){ bnWhh[i] = f2b(nWhh[i]); return; }
  i -= 49152;
  { int k = i>>7, n = i&127; baW1T[n*128+k] = f2b(aW1[i]); }
}

__global__ void hist_kernel(const int* __restrict__ dst, int* __restrict__ counts, int n){
  int i = blockIdx.x*blockDim.x + threadIdx.x; if (i<n) atomicAdd(&counts[dst[i]],1);
}
// parallel exclusive scan over counts -> rowp/cursor (3 phases)
__global__ void scanA_kernel(const int* __restrict__ counts, int* __restrict__ rowp,
                             int* __restrict__ bsum, int n){
  __shared__ int buf[1024];
  const int gid = blockIdx.x*1024 + threadIdx.x;
  int v = (gid<n) ? counts[gid] : 0;
  buf[threadIdx.x]=v; __syncthreads();
  for (int off=1; off<1024; off<<=1){
    int x = (threadIdx.x>=off) ? buf[threadIdx.x-off] : 0;
    __syncthreads();
    buf[threadIdx.x]+=x; __syncthreads();
  }
  if (gid<n) rowp[gid] = buf[threadIdx.x]-v;          // block-local exclusive
  if (threadIdx.x==1023) bsum[blockIdx.x]=buf[1023];  // block total
}
__global__ void scanB_kernel(int* bsum, int* rowp, int nb, int n){
  if (threadIdx.x==0 && blockIdx.x==0){
    int run=0;
    for (int b=0;b<nb;++b){ int t=bsum[b]; bsum[b]=run; run+=t; }
    rowp[n]=run;
  }
}
__global__ void scanC_kernel(int* __restrict__ rowp, int* __restrict__ cursor,
                             const int* __restrict__ bsum, int n){
  const int gid = blockIdx.x*1024 + threadIdx.x;
  if (gid<n){ int v = rowp[gid]+bsum[blockIdx.x]; rowp[gid]=v; cursor[gid]=v; }
}
__global__ void scatter_kernel(const int* __restrict__ dst, int* __restrict__ cursor,
                               int* __restrict__ eids, int n){
  int i = blockIdx.x*blockDim.x + threadIdx.x;
  if (i<n){ int p = atomicAdd(&cursor[dst[i]],1); eids[p]=i; }
}
// permuted edge endpoints (CSR order by dst)
__global__ void perm_kernel(const int* __restrict__ eids, const int* __restrict__ src,
                            const int* __restrict__ dst, int* __restrict__ srcp,
                            int* __restrict__ dstp, int n){
  int i = blockIdx.x*blockDim.x + threadIdx.x;
  if (i<n){ int e=eids[i]; srcp[i]=src[e]; dstp[i]=dst[e]; }
}

// ---------- edge GRU + attention MLP (v16: v12 structure + fused ef ingest) ----------
// v12 hot-loop (converged optimum: 294us): 512 thr = 8 waves x 16 edges, single
// 36KB frag-major weight buffer, 2-barrier chunk loop, launch_bounds(512,4).
// Template<IT0>: it0 reads ef directly from fp32 ef_in (original order via eids)
// -- ae gathered+converted once, h0 scattered fp32 (L3-resident) -- deleting the
// separate efgather pass (~48us). it1 instantiation is bit-identical to v12's
// kernel (VGPR 64 preserved; remat/occupancy risk confined to it0 variant).
template<bool IT0>
__global__ __launch_bounds__(512, 4)
void edge_kernel(const int* __restrict__ srcp, const int* __restrict__ dstp,
                 const int* __restrict__ eids,
                 const u16* __restrict__ nfb, u16* __restrict__ efb,
                 const float* __restrict__ ef32in,
                 const u16* __restrict__ Wih, const u16* __restrict__ Whh,
                 const float* __restrict__ bih, const float* __restrict__ bhh,
                 const u16* __restrict__ aW1T, const float* __restrict__ ab1,
                 const float* __restrict__ aW2, const float* __restrict__ ab2,
                 float* __restrict__ logits, float* __restrict__ ef32out)
{
  __shared__ __align__(16) u16 wbuf[36*512];   // 36 KB, frag-major
  const int wave = threadIdx.x>>6, lane = threadIdx.x&63;
  const int r16 = lane&15, kq = lane>>4;
  const long base = (long)blockIdx.x*128 + wave*16;
  const long e = base + r16;

  // cooperative staging of chunk c's weight frags (c=8 -> attention weights)
  auto stage = [&](int c){
    if (c < 8){
      for (int f = wave; f < 36; f += 8){
        const u16* g;
        if (f < 24){ const int gt = f>>3, s = f&7;
          g = Wih + (long)(gt*128 + c*16 + r16)*256 + s*32 + kq*8; }
        else { const int q = f-24, gt = q>>2, s = q&3;
          g = Whh + (long)(gt*128 + c*16 + r16)*128 + s*32 + kq*8; }
        GLOAD_LDS(g, wbuf + f*512);
      }
    } else {
      for (int f = wave; f < 32; f += 8){
        const int t = f>>2, s = f&3;
        GLOAD_LDS(aW1T + (long)(t*16 + r16)*128 + s*32 + kq*8, wbuf + f*512);
      }
    }
  };

  // A-fragments, loaded ONCE into registers: gi K=256 (src|dst), gh K=128 (ef)
  const u16* sp = nfb + (long)srcp[e]*DIM;
  const u16* dp = nfb + (long)dstp[e]*DIM;
  const u16* ep = efb + e*DIM;
  bf16x8 ag[8], ae[4];
#pragma unroll
  for (int s=0;s<4;++s){
    ag[s]   = ldb8(sp + s*32 + kq*8);
    ag[s+4] = ldb8(dp + s*32 + kq*8);
  }
  if (IT0){
    const float* epf = ef32in + (long)eids[e]*DIM;
#pragma unroll
    for (int s=0;s<4;++s){
      float4 f0 = *reinterpret_cast<const float4*>(epf + s*32 + kq*8);
      float4 f1 = *reinterpret_cast<const float4*>(epf + s*32 + kq*8 + 4);
      bf16x8 t;
      t[0]=(__bf16)f0.x; t[1]=(__bf16)f0.y; t[2]=(__bf16)f0.z; t[3]=(__bf16)f0.w;
      t[4]=(__bf16)f1.x; t[5]=(__bf16)f1.y; t[6]=(__bf16)f1.z; t[7]=(__bf16)f1.w;
      ae[s] = t;
    }
  } else {
#pragma unroll
    for (int s=0;s<4;++s) ae[s] = ldb8(ep + s*32 + kq*8);
  }
  // original edge ids for the 4 rows this lane epilogues
  int oe[4];
#pragma unroll
  for (int r=0;r<4;++r) oe[r] = eids[base + kq*4 + r];

  stage(0);
  __syncthreads();

  // hoisted bases: all epilogue accesses are base + r*DIM + c*16 (imm-friendly)
  u16* ebase = efb + (base + kq*4)*DIM + r16;
  const float* bi0 = bih + r16;
  const float* bh0 = bhh + r16;

  const f32x4 vzero = {0.f,0.f,0.f,0.f};
  const u16* lbase = wbuf + lane*8;   // frag f => lbase + f*512 (u16 units)

#pragma unroll 1
  for (int c=0;c<8;++c){
    const int c16 = c*16;
    const float bir=bi0[c16], biz=bi0[c16+DIM], bin=bi0[c16+2*DIM];
    const float bhr=bh0[c16], bhz=bh0[c16+DIM], bhn=bh0[c16+2*DIM];
    float h0p[4];
    if (IT0){
#pragma unroll
      for (int r=0;r<4;++r) h0p[r] = ef32in[(long)oe[r]*DIM + c16 + r16];  // L3-hot
    } else {
#pragma unroll
      for (int r=0;r<4;++r) h0p[r] = b2f(ebase[r*DIM + c16]);             // L1/L2-hot
    }

    f32x4 ar=vzero, az=vzero, an=vzero, hr=vzero, hz=vzero, hn=vzero;
#pragma unroll
    for (int s=0;s<8;++s){
      ar = MFMA16(ag[s], ldb8(lbase + ( s   )*512), ar,0,0,0);
      az = MFMA16(ag[s], ldb8(lbase + ( 8+s )*512), az,0,0,0);
      an = MFMA16(ag[s], ldb8(lbase + (16+s )*512), an,0,0,0);
    }
#pragma unroll
    for (int s=0;s<4;++s){
      hr = MFMA16(ae[s], ldb8(lbase + (24+s)*512), hr,0,0,0);
      hz = MFMA16(ae[s], ldb8(lbase + (28+s)*512), hz,0,0,0);
      hn = MFMA16(ae[s], ldb8(lbase + (32+s)*512), hn,0,0,0);
    }
    __syncthreads();              // all waves done reading wbuf
    stage(c+1);                   // refill; drains at end-of-chunk barrier
    float uv[4];
#pragma unroll
    for (int r=0;r<4;++r){
      float rg = sigm(ar[r]+bir + hr[r]+bhr);
      float zg = sigm(az[r]+biz + hz[r]+bhz);
      float ng = tanh_(an[r]+bin + rg*(hn[r]+bhn));
      float u  = ng + zg*(h0p[r]-ng);
      ebase[r*DIM + c16] = f2b(u);
      uv[r] = u;
    }
    if (ef32out){
#pragma unroll
      for (int r=0;r<4;++r) ef32out[(long)oe[r]*DIM + c16 + r16] = uv[r];
    }
    __syncthreads();              // wbuf refilled; stores drained
  }

  // ----- attention MLP: chunk 8 (aW1T) in wbuf; uef row re-read L1-hot -----
  bf16x8 ua[4];
#pragma unroll
  for (int s=0;s<4;++s) ua[s] = ldb8(ep + s*32 + kq*8);
  float part[4] = {0.f,0.f,0.f,0.f};
#pragma unroll 1
  for (int t=0;t<8;++t){
    f32x4 h = vzero;
#pragma unroll
    for (int s=0;s<4;++s)
      h = MFMA16(ua[s], ldb8(lbase + (t*4+s)*512), h,0,0,0);
    const int cc = t*16 + r16;
    const float b1 = ab1[cc], w2 = aW2[cc];
#pragma unroll
    for (int r=0;r<4;++r) part[r] += fmaxf(h[r]+b1, 0.f)*w2;
  }
#pragma unroll
  for (int off=1; off<16; off<<=1){
#pragma unroll
    for (int r=0;r<4;++r) part[r] += __shfl_xor(part[r], off, 64);
  }
  if (r16==0){
    const float b2v = ab2[0];
#pragma unroll
    for (int r=0;r<4;++r) logits[base + kq*4 + r] = part[r] + b2v;   // sequential
  }
}

// ---------- softmax + weighted aggregation (permuted CSR: fully sequential) ----------
__global__ __launch_bounds__(256)
void agg_kernel(const int* __restrict__ rowp, const float* __restrict__ logits,
                const u16* __restrict__ uefb, u16* __restrict__ aggb)
{
  const int wave = threadIdx.x>>6, lane = threadIdx.x&63;
  const int v = blockIdx.x*4 + wave;
  if (v>=NN) return;
  const int p0 = rowp[v], p1 = rowp[v+1], deg = p1-p0;
  float ax=0.f, ay=0.f;
  if (deg>0){
    float mx = -__builtin_inff();
    for (int i=p0+lane; i<p1; i+=64) mx = fmaxf(mx, logits[i]);
#pragma unroll
    for (int off=32; off; off>>=1) mx = fmaxf(mx, __shfl_xor(mx, off, 64));
    float ss = 0.f;
    for (int i=p0+lane; i<p1; i+=64) ss += __expf(logits[i] - mx);
#pragma unroll
    for (int off=32; off; off>>=1) ss += __shfl_xor(ss, off, 64);
    const float inv = 1.0f/ss;
    int i = p0;
    for (; i+2<=p1; i+=2){
      const float l0 = logits[i], l1 = logits[i+1];
      const unsigned q0 = *reinterpret_cast<const unsigned*>(uefb + (long)i*DIM + lane*2);
      const unsigned q1 = *reinterpret_cast<const unsigned*>(uefb + (long)(i+1)*DIM + lane*2);
      const float a0 = __expf(l0-mx)*inv, a1 = __expf(l1-mx)*inv;
      ax += a0*b2f((u16)q0) + a1*b2f((u16)q1);
      ay += a0*b2f((u16)(q0>>16)) + a1*b2f((u16)(q1>>16));
    }
    if (i<p1){
      const float a0 = __expf(logits[i]-mx)*inv;
      const unsigned q0 = *reinterpret_cast<const unsigned*>(uefb + (long)i*DIM + lane*2);
      ax += a0*b2f((u16)q0);
      ay += a0*b2f((u16)(q0>>16));
    }
  }
  unsigned pack = (unsigned)f2b(ax) | ((unsigned)f2b(ay)<<16);
  *reinterpret_cast<unsigned*>(aggb + (long)v*DIM + lane*2) = pack;
}

// ---------- node GRU (double-buffered staged weights, 8 waves x 16 nodes) ----------
__global__ __launch_bounds__(512, 4)
void node_kernel(const u16* __restrict__ aggb, u16* __restrict__ nfb,
                 const float* nf32, float* unf32,            // may alias (in-place iter 2)
                 const u16* __restrict__ Wih, const u16* __restrict__ Whh,
                 const float* __restrict__ bih, const float* __restrict__ bhh)
{
  __shared__ __align__(16) u16 wbuf[2*24*512];   // 48 KB, frag-major, double-buffered
  const int wave = threadIdx.x>>6, lane = threadIdx.x&63;
  const int r16 = lane&15, kq = lane>>4;
  const long tbase = (long)blockIdx.x*128 + wave*16;
  const long v = tbase + r16;
  const long vcl = (v < NN) ? v : (NN-1);

  auto stage = [&](int c){
    if (c >= 8) return;
    u16* bufp = wbuf + (c&1)*24*512;
    for (int f = wave; f < 24; f += 8){
      const u16* g;
      if (f < 12){ const int gt = f>>2, s = f&3;
        g = Wih + (long)(gt*128 + c*16 + r16)*128 + s*32 + kq*8; }
      else { const int q = f-12, gt = q>>2, s = q&3;
        g = Whh + (long)(gt*128 + c*16 + r16)*128 + s*32 + kq*8; }
      GLOAD_LDS(g, bufp + f*512);
    }
  };

  bf16x8 xa[4], ha[4];
#pragma unroll
  for (int s=0;s<4;++s){
    xa[s] = ldb8(aggb + vcl*DIM + s*32 + kq*8);
    ha[s] = ldb8(nfb  + vcl*DIM + s*32 + kq*8);
  }
  stage(0);
  __syncthreads();

  const f32x4 vzero = {0.f,0.f,0.f,0.f};

#pragma unroll 1
  for (int c=0;c<8;++c){
    stage(c+1);
    const int oc = c*16 + r16;
    const float bir=bih[oc], biz=bih[DIM+oc], bin=bih[2*DIM+oc];
    const float bhr=bhh[oc], bhz=bhh[DIM+oc], bhn=bhh[2*DIM+oc];
    float h0p[4];
#pragma unroll
    for (int r=0;r<4;++r){
      const long rr = tbase + kq*4 + r;
      h0p[r] = (rr < NN) ? nf32[rr*DIM+oc] : 0.f;
    }
    const u16* lb = wbuf + (c&1)*24*512 + lane*8;
    f32x4 ar=vzero, az=vzero, an=vzero, hr=vzero, hz=vzero, hn=vzero;
#pragma unroll
    for (int s=0;s<4;++s){
      ar=MFMA16(xa[s], ldb8(lb + ( s   )*512), ar,0,0,0);
      az=MFMA16(xa[s], ldb8(lb + ( 4+s)*512), az,0,0,0);
      an=MFMA16(xa[s], ldb8(lb + ( 8+s)*512), an,0,0,0);
      hr=MFMA16(ha[s], ldb8(lb + (12+s)*512), hr,0,0,0);
      hz=MFMA16(ha[s], ldb8(lb + (16+s)*512), hz,0,0,0);
      hn=MFMA16(ha[s], ldb8(lb + (20+s)*512), hn,0,0,0);
    }
#pragma unroll
    for (int r=0;r<4;++r){
      const long rr = tbase + kq*4 + r;
      if (rr < NN){
        float rg = sigm(ar[r]+bir + hr[r]+bhr);
        float zg = sigm(az[r]+biz + hz[r]+bhz);
        float ng = tanh_(an[r]+bin + rg*(hn[r]+bhn));
        float u  = ng + zg*(h0p[r]-ng);
        unf32[rr*DIM+oc] = u;
        nfb[rr*DIM+oc] = f2b(u);   // safe: nfb reads preloaded before loop
      }
    }
    __syncthreads();
  }
}

extern "C" void kernel_launch(void* const* d_in, const int* in_sizes, int n_in,
                              void* d_out, int out_size, void* d_ws, size_t ws_size,
                              hipStream_t stream)
{
  const float* nf_in = (const float*)d_in[0];
  const float* ef_in = (const float*)d_in[1];
  const int*   src   = (const int*)d_in[2];
  const int*   dst   = (const int*)d_in[3];
  const float* eWih  = (const float*)d_in[4];
  const float* eWhh  = (const float*)d_in[5];
  const float* ebih  = (const float*)d_in[6];
  const float* ebhh  = (const float*)d_in[7];
  const float* nWih  = (const float*)d_in[8];
  const float* nWhh  = (const float*)d_in[9];
  const float* nbih  = (const float*)d_in[10];
  const float* nbhh  = (const float*)d_in[11];
  const float* aW1   = (const float*)d_in[12];
  const float* ab1   = (const float*)d_in[13];
  const float* aW2   = (const float*)d_in[14];
  const float* ab2   = (const float*)d_in[15];

  float* nf_out = (float*)d_out;
  float* ef_out = nf_out + (size_t)NN*DIM;

  // workspace carve (~135 MB)
  char* p = (char*)d_ws;
  auto carve = [&](size_t bytes)->void*{ void* r = (void*)p; p += (bytes + 255) & ~(size_t)255; return r; };
  u16* efb    = (u16*)carve((size_t)NE*DIM*2);      // permuted (CSR order) ef state
  u16* nfb    = (u16*)carve((size_t)NN*DIM*2);
  u16* aggb   = (u16*)carve((size_t)NN*DIM*2);
  float* logits = (float*)carve((size_t)NE*4);      // permuted order
  int* eids   = (int*)carve((size_t)NE*4);
  int* srcp   = (int*)carve((size_t)NE*4);
  int* dstp   = (int*)carve((size_t)NE*4);
  int* counts = (int*)carve((size_t)NN*4);
  int* rowp   = (int*)carve((size_t)(NN+1)*4);
  int* cursor = (int*)carve((size_t)NN*4);
  int* bsum   = (int*)carve((size_t)64*4);
  u16* bWih   = (u16*)carve((size_t)384*256*2);
  u16* bWhh   = (u16*)carve((size_t)384*128*2);
  u16* bnWih  = (u16*)carve((size_t)384*128*2);
  u16* bnWhh  = (u16*)carve((size_t)384*128*2);
  u16* baW1T  = (u16*)carve((size_t)128*128*2);

  const int NB = (NN + 1023)/1024;   // 49 scan blocks

  // CSR over dst + permutation (constant across iterations)
  hipMemsetAsync(counts, 0, (size_t)NN*4, stream);
  hist_kernel<<<(NE+255)/256,256,0,stream>>>(dst, counts, NE);
  scanA_kernel<<<NB,1024,0,stream>>>(counts, rowp, bsum, NN);
  scanB_kernel<<<1,64,0,stream>>>(bsum, rowp, NB, NN);
  scanC_kernel<<<NB,1024,0,stream>>>(rowp, cursor, bsum, NN);
  scatter_kernel<<<(NE+255)/256,256,0,stream>>>(dst, cursor, eids, NE);
  perm_kernel<<<(NE+255)/256,256,0,stream>>>(eids, src, dst, srcp, dstp, NE);

  // bf16 conversions (once per launch); ef ingested directly by edge it0
  f2b_kernel<<<2048,256,0,stream>>>(nf_in, nfb, NN*DIM/4);
  wprep_kernel<<<1024,256,0,stream>>>(eWih, eWhh, nWih, nWhh, aW1,
                                      bWih, bWhh, bnWih, bnWhh, baW1T);

  // ---- iteration 0: edge reads ef from fp32 input (fused gather+convert) ----
  edge_kernel<true><<<NE/128,512,0,stream>>>(srcp, dstp, eids, nfb, efb, ef_in,
                                             bWih, bWhh, ebih, ebhh,
                                             baW1T, ab1, aW2, ab2, logits, nullptr);
  agg_kernel<<<(NN+3)/4,256,0,stream>>>(rowp, logits, efb, aggb);
  node_kernel<<<(NN+127)/128,512,0,stream>>>(aggb, nfb, nf_in, nf_out,
                                             bnWih, bnWhh, nbih, nbhh);
  // ---- iteration 1: edge reads bf16 efb state; writes fp32 ef_out ----
  edge_kernel<false><<<NE/128,512,0,stream>>>(srcp, dstp, eids, nfb, efb, nullptr,
                                              bWih, bWhh, ebih, ebhh,
                                              baW1T, ab1, aW2, ab2, logits, ef_out);
  agg_kernel<<<(NN+3)/4,256,0,stream>>>(rowp, logits, efb, aggb);
  node_kernel<<<(NN+127)/128,512,0,stream>>>(aggb, nfb, nf_out, nf_out,
                                             bnWih, bnWhh, nbih, nbhh);
}